// Round 6
// baseline (205.695 us; speedup 1.0000x reference)
//
#include <hip/hip_runtime.h>
#include <hip/hip_bf16.h>

typedef __attribute__((ext_vector_type(8))) short short8;
typedef __attribute__((ext_vector_type(4))) float f32x4;
typedef unsigned short ushort;

// ---------------- gamma = mean(|W|) + 1e-6, deterministic two-stage ----------------

__global__ void kabs_partial(const float* __restrict__ W, double* __restrict__ part, int n) {
    __shared__ double sd[256];
    const int tid = threadIdx.x;
    double s = 0.0;
    for (int i = blockIdx.x * blockDim.x + tid; i < n; i += gridDim.x * blockDim.x)
        s += (double)fabsf(W[i]);
    sd[tid] = s;
    __syncthreads();
    for (int off = 128; off > 0; off >>= 1) {
        if (tid < off) sd[tid] += sd[tid + off];
        __syncthreads();
    }
    if (tid == 0) part[blockIdx.x] = sd[0];
}

__global__ void kgamma(const double* __restrict__ part, float* __restrict__ gout, int nelem) {
    __shared__ double sd[256];
    const int tid = threadIdx.x;
    double s = part[tid] + part[tid + 256] + part[tid + 512] + part[tid + 768];
    sd[tid] = s;
    __syncthreads();
    for (int off = 128; off > 0; off >>= 1) {
        if (tid < off) sd[tid] += sd[tid + off];
        __syncthreads();
    }
    if (tid == 0) gout[0] = (float)(sd[0] / (double)nelem) + 1e-6f;
}

// ---------------- quantizers: write bf16 {-1,0,+1} bit patterns ----------------

__device__ __forceinline__ unsigned int qw_h(float w, float g) {
    float t = fabsf(w) / g;
    unsigned int u = __float_as_uint(w);
    unsigned int h = 0x3F80u | ((u >> 16) & 0x8000u);   // +-1.0 bf16
    return (rintf(t) >= 1.0f) ? h : 0u;
}

__global__ void kquant_w(const float4* __restrict__ W4, unsigned short* __restrict__ Wq,
                         const float* __restrict__ gptr, int n4) {
    int i = blockIdx.x * blockDim.x + threadIdx.x;
    if (i >= n4) return;
    const float g = *gptr;
    float4 w = W4[i];
    unsigned int h0 = qw_h(w.x, g) | (qw_h(w.y, g) << 16);
    unsigned int h1 = qw_h(w.z, g) | (qw_h(w.w, g) << 16);
    ((uint2*)Wq)[i] = make_uint2(h0, h1);
}

__device__ __forceinline__ unsigned int sgn_h(float a) {
    unsigned int u = __float_as_uint(a);
    return (u & 0x7FFFFFFFu) ? (0x3F80u | ((u >> 16) & 0x8000u)) : 0u;
}
__device__ __forceinline__ unsigned int sgn2(float a, float b) {
    return sgn_h(a) | (sgn_h(b) << 16);
}

__global__ void kquant_x(const float4* __restrict__ X4, uint4* __restrict__ Xq, size_t n8) {
    size_t i = (size_t)blockIdx.x * blockDim.x + threadIdx.x;
    if (i >= n8) return;
    float4 a = X4[2 * i], b = X4[2 * i + 1];
    uint4 o;
    o.x = sgn2(a.x, a.y);
    o.y = sgn2(a.z, a.w);
    o.z = sgn2(b.x, b.y);
    o.w = sgn2(b.z, b.w);
    Xq[i] = o;
}

// ---------------- 256x256 bf16 MFMA GEMM: C[M][N] = A[M][K] * B[N][K]^T ----------------
// 8 waves (2M x 4N), per-wave 128x64 output. LDS [dbuf][half][128][64] per operand.
// Deep pipeline: at tile-t ph0, the nxt buffer is fully dead (double-buffer invariant),
// so ALL 8 loads of tile t+1 issue at ph0; one vmcnt(8) then waits only on tile-t loads
// issued 4 phases (~1400 cyc) earlier. One certify barrier makes cross-wave LDS writes
// visible (vmcnt is per-wave). ph0 reads must follow the certify barrier; ph1-3 keep the
// read-before-barrier overlap. vmcnt never drains to 0 except on the last tile.

#define STAGE_HALF(SRC, DST, BASE_ROW, KB)                                                  \
    {                                                                                       \
        _Pragma("unroll")                                                                   \
        for (int l = 0; l < 2; ++l) {                                                       \
            const int r_ = l * 64 + srow;                                                   \
            const ushort* g_ = (SRC) + (size_t)((BASE_ROW) + r_) * K + (KB) +               \
                               (sec ^ ((r_ & 7) << 3));                                     \
            __builtin_amdgcn_global_load_lds(                                               \
                (const __attribute__((address_space(1))) unsigned int*)g_,                  \
                (__attribute__((address_space(3))) unsigned int*)&(DST)[r_][sec], 16, 0, 0);\
        }                                                                                   \
    }

__global__ __launch_bounds__(512, 2) void kgemm(const ushort* __restrict__ A,
                                                const ushort* __restrict__ B,
                                                float* __restrict__ C,
                                                int M, int N, int K) {
    __shared__ ushort As[2][2][128][64];
    __shared__ ushort Bs[2][2][128][64];

    const int tid = threadIdx.x;
    const int lane = tid & 63;
    const int wid = tid >> 6;      // 0..7
    const int wm = wid >> 2;       // 0..1  (M sub-block within each half)
    const int wn = wid & 3;        // 0..3  (N sub-block)

    // T1: XCD-aware block swizzle (grid % 8 == 0 here)
    int bid = blockIdx.x;
    const int nwg = gridDim.x;
    if ((nwg & 7) == 0) bid = (bid & 7) * (nwg >> 3) + (bid >> 3);
    const int nbn = N >> 8;
    const int bm = bid / nbn, bn = bid % nbn;
    const int row0 = bm << 8, col0 = bn << 8;

    const int lr = lane & 15;
    const int lk = (lane >> 4) * 8;

    // staging thread mapping: 512 threads cover 64 rows x 64 cols per load instr
    const int srow = tid >> 3;          // 0..63
    const int sec  = (tid & 7) * 8;     // element chunk (8 bf16 = 16 B)

    f32x4 acc[8][4] = {};
    const int NT = K >> 6;

    // ---- prologue: issue tile 0 stages only; loop's first vmcnt(8)+barrier certifies
    STAGE_HALF(B, Bs[0][0], col0, 0);
    STAGE_HALF(B, Bs[0][1], col0 + 128, 0);
    STAGE_HALF(A, As[0][0], row0, 0);
    STAGE_HALF(A, As[0][1], row0 + 128, 0);

    int cur = 0;
    for (int t = 0; t < NT; ++t) {
        const int nxt = cur ^ 1;
        const int kb = (t + 1) << 6;

        // ---- ph0: issue ENTIRE tile t+1 into nxt (dead since last tile's end barrier),
        //      counted wait covers tile t's 8 loads (issued one full tile ago)
        if (t + 1 < NT) {
            STAGE_HALF(B, Bs[nxt][0], col0, kb);
            STAGE_HALF(B, Bs[nxt][1], col0 + 128, kb);
            STAGE_HALF(A, As[nxt][0], row0, kb);
            STAGE_HALF(A, As[nxt][1], row0 + 128, kb);
            asm volatile("s_waitcnt vmcnt(8)" ::: "memory");
        } else {
            asm volatile("s_waitcnt vmcnt(0)" ::: "memory");
        }
        __builtin_amdgcn_s_barrier();   // certify buf[cur] across all waves
        asm volatile("" ::: "memory");

        // ph0 fragment reads (after certify): all B frags + A m=0,1
        short8 bv[4][2];
#pragma unroll
        for (int n = 0; n < 4; ++n) {
            const int rb = (wn & 1) * 64 + n * 16 + lr;
#pragma unroll
            for (int ks = 0; ks < 2; ++ks)
                bv[n][ks] = *(const short8*)&Bs[cur][wn >> 1][rb][(ks * 32 + lk) ^ ((rb & 7) << 3)];
        }
        {
            short8 av[2][2];
#pragma unroll
            for (int mi = 0; mi < 2; ++mi) {
                const int ra = wm * 64 + mi * 16 + lr;
#pragma unroll
                for (int ks = 0; ks < 2; ++ks)
                    av[mi][ks] = *(const short8*)&As[cur][0][ra][(ks * 32 + lk) ^ ((ra & 7) << 3)];
            }
            asm volatile("s_waitcnt lgkmcnt(0)" ::: "memory");
            __builtin_amdgcn_s_setprio(1);
#pragma unroll
            for (int mi = 0; mi < 2; ++mi)
#pragma unroll
                for (int n = 0; n < 4; ++n)
#pragma unroll
                    for (int ks = 0; ks < 2; ++ks)
                        acc[mi][n] = __builtin_amdgcn_mfma_f32_16x16x32_bf16(
                            av[mi][ks], bv[n][ks], acc[mi][n], 0, 0, 0);
            __builtin_amdgcn_s_setprio(0);
            asm volatile("" ::: "memory");
            __builtin_amdgcn_s_barrier();
            asm volatile("" ::: "memory");
        }

        // ---- ph1..ph3: reads overlap the pre-MFMA barrier wait
#pragma unroll
        for (int ph = 1; ph < 4; ++ph) {
            short8 av[2][2];
#pragma unroll
            for (int mi = 0; mi < 2; ++mi) {
                const int m = ph * 2 + mi;
                const int ra = wm * 64 + (m & 3) * 16 + lr;
#pragma unroll
                for (int ks = 0; ks < 2; ++ks)
                    av[mi][ks] = *(const short8*)&As[cur][m >> 2][ra][(ks * 32 + lk) ^ ((ra & 7) << 3)];
            }
            __builtin_amdgcn_s_barrier();
            asm volatile("s_waitcnt lgkmcnt(0)" ::: "memory");
            __builtin_amdgcn_s_setprio(1);
#pragma unroll
            for (int mi = 0; mi < 2; ++mi)
#pragma unroll
                for (int n = 0; n < 4; ++n)
#pragma unroll
                    for (int ks = 0; ks < 2; ++ks)
                        acc[ph * 2 + mi][n] = __builtin_amdgcn_mfma_f32_16x16x32_bf16(
                            av[mi][ks], bv[n][ks], acc[ph * 2 + mi][n], 0, 0, 0);
            __builtin_amdgcn_s_setprio(0);
            asm volatile("" ::: "memory");
            __builtin_amdgcn_s_barrier();   // protects cur from next tile's ph0 stages
            asm volatile("" ::: "memory");
        }
        cur = nxt;
    }

    // ---- epilogue: C/D layout col = lane&15, row = (lane>>4)*4 + reg (m89-verified)
#pragma unroll
    for (int m = 0; m < 8; ++m) {
        const int grow = row0 + (m >> 2) * 128 + wm * 64 + (m & 3) * 16 + (lane >> 4) * 4;
#pragma unroll
        for (int n = 0; n < 4; ++n) {
            float* cp = C + (size_t)grow * N + col0 + wn * 64 + n * 16 + (lane & 15);
#pragma unroll
            for (int r = 0; r < 4; ++r)
                cp[(size_t)r * N] = acc[m][n][r];
        }
    }
}

// ---------------- correct-but-slow fallback if workspace is tiny ----------------

__global__ void knaive(const float* __restrict__ X, const float* __restrict__ W,
                       const float* __restrict__ gptr, float* __restrict__ out,
                       int N, int K) {
    size_t idx = (size_t)blockIdx.x * blockDim.x + threadIdx.x;
    const int m = (int)(idx / N), n = (int)(idx % N);
    const float g = *gptr;
    const float* xr = X + (size_t)m * K;
    const float* wrow = W + (size_t)n * K;
    float acc = 0.f;
    for (int k = 0; k < K; ++k) {
        float xv = xr[k];
        float xs = (xv > 0.f) ? 1.f : ((xv < 0.f) ? -1.f : 0.f);
        float w = wrow[k];
        float wq = (rintf(fabsf(w) / g) >= 1.f) ? ((w < 0.f) ? -1.f : 1.f) : 0.f;
        acc += xs * wq;
    }
    out[idx] = acc;
}

// ---------------- launch ----------------

extern "C" void kernel_launch(void* const* d_in, const int* in_sizes, int n_in,
                              void* d_out, int out_size, void* d_ws, size_t ws_size,
                              hipStream_t stream) {
    const float* x = (const float*)d_in[0];
    const float* W = (const float*)d_in[1];
    float* out = (float*)d_out;

    const int K = 2048;                 // in_features
    const int N = in_sizes[1] / K;      // out_features = 2048
    const int M = in_sizes[0] / K;      // 4*4096 = 16384
    const int nW = in_sizes[1];

    char* ws = (char*)d_ws;
    double* partials = (double*)ws;                       // 1024 doubles = 8 KB
    float* gamma = (float*)(ws + 8192);
    ushort* wq = (ushort*)(ws + 16384);
    ushort* xq = (ushort*)(ws + 16384 + (size_t)N * K * 2);
    const size_t need = 16384 + (size_t)N * K * 2 + (size_t)M * K * 2;

    kabs_partial<<<1024, 256, 0, stream>>>(W, partials, nW);
    kgamma<<<1, 256, 0, stream>>>(partials, gamma, nW);

    if (ws_size >= need && (M % 256) == 0 && (N % 256) == 0 && (K % 64) == 0) {
        kquant_w<<<nW / (256 * 4), 256, 0, stream>>>((const float4*)W, wq, gamma, nW / 4);
        const size_t n8 = (size_t)M * K / 8;
        kquant_x<<<(unsigned)(n8 / 256), 256, 0, stream>>>((const float4*)x, (uint4*)xq, n8);
        kgemm<<<(M / 256) * (N / 256), 512, 0, stream>>>(xq, wq, out, M, N, K);
    } else {
        knaive<<<(unsigned)((size_t)M * N / 256), 256, 0, stream>>>(x, W, gamma, out, N, K);
    }
}

// Round 7
// 175.025 us; speedup vs baseline: 1.1752x; 1.1752x over previous
//
#include <hip/hip_runtime.h>
#include <hip/hip_bf16.h>

typedef __attribute__((ext_vector_type(8))) short short8;
typedef __attribute__((ext_vector_type(4))) float f32x4;
typedef unsigned short ushort;

// ---------------- gamma = mean(|W|) + 1e-6, deterministic two-stage ----------------

__global__ void kabs_partial(const float* __restrict__ W, double* __restrict__ part, int n) {
    __shared__ double sd[256];
    const int tid = threadIdx.x;
    double s = 0.0;
    for (int i = blockIdx.x * blockDim.x + tid; i < n; i += gridDim.x * blockDim.x)
        s += (double)fabsf(W[i]);
    sd[tid] = s;
    __syncthreads();
    for (int off = 128; off > 0; off >>= 1) {
        if (tid < off) sd[tid] += sd[tid + off];
        __syncthreads();
    }
    if (tid == 0) part[blockIdx.x] = sd[0];
}

__global__ void kgamma(const double* __restrict__ part, float* __restrict__ gout, int nelem) {
    __shared__ double sd[256];
    const int tid = threadIdx.x;
    double s = part[tid] + part[tid + 256] + part[tid + 512] + part[tid + 768];
    sd[tid] = s;
    __syncthreads();
    for (int off = 128; off > 0; off >>= 1) {
        if (tid < off) sd[tid] += sd[tid + off];
        __syncthreads();
    }
    if (tid == 0) gout[0] = (float)(sd[0] / (double)nelem) + 1e-6f;
}

// ---------------- quantizers: write bf16 {-1,0,+1} bit patterns ----------------

__device__ __forceinline__ unsigned int qw_h(float w, float g) {
    float t = fabsf(w) / g;
    unsigned int u = __float_as_uint(w);
    unsigned int h = 0x3F80u | ((u >> 16) & 0x8000u);   // +-1.0 bf16
    return (rintf(t) >= 1.0f) ? h : 0u;
}

__global__ void kquant_w(const float4* __restrict__ W4, unsigned short* __restrict__ Wq,
                         const float* __restrict__ gptr, int n4) {
    int i = blockIdx.x * blockDim.x + threadIdx.x;
    if (i >= n4) return;
    const float g = *gptr;
    float4 w = W4[i];
    unsigned int h0 = qw_h(w.x, g) | (qw_h(w.y, g) << 16);
    unsigned int h1 = qw_h(w.z, g) | (qw_h(w.w, g) << 16);
    ((uint2*)Wq)[i] = make_uint2(h0, h1);
}

__device__ __forceinline__ unsigned int sgn_h(float a) {
    unsigned int u = __float_as_uint(a);
    return (u & 0x7FFFFFFFu) ? (0x3F80u | ((u >> 16) & 0x8000u)) : 0u;
}
__device__ __forceinline__ unsigned int sgn2(float a, float b) {
    return sgn_h(a) | (sgn_h(b) << 16);
}

__global__ void kquant_x(const float4* __restrict__ X4, uint4* __restrict__ Xq, size_t n8) {
    size_t i = (size_t)blockIdx.x * blockDim.x + threadIdx.x;
    if (i >= n8) return;
    float4 a = X4[2 * i], b = X4[2 * i + 1];
    uint4 o;
    o.x = sgn2(a.x, a.y);
    o.y = sgn2(a.z, a.w);
    o.z = sgn2(b.x, b.y);
    o.w = sgn2(b.z, b.w);
    Xq[i] = o;
}

// ---------------- 256x256 m201-style 8-phase bf16 MFMA GEMM: C = A * B^T ----------------
// 8 waves (2M x 4N), per-wave 128x64 output. Tile tau lives in buf tau&1 (static).
// Per 8-phase iteration (tiles t even @buf0 ph1-4, t+1 @buf1 ph5-8), staging is spread
// ONE half-tile (2 gload_lds) per phase; vmcnt(6) only at ph4 (certifies t+1) and ph8
// (certifies t+2). Every awaited load has >=3 phases of slack. Stage calendar obeys
// "stage a region only after the barrier following its last read".

#define STAGE_HALF(SRC, DST, BASE_ROW, KB)                                                  \
    {                                                                                       \
        _Pragma("unroll")                                                                   \
        for (int l = 0; l < 2; ++l) {                                                       \
            const int r_ = l * 64 + srow;                                                   \
            const ushort* g_ = (SRC) + (size_t)((BASE_ROW) + r_) * K + (KB) +               \
                               (sec ^ ((r_ & 7) << 3));                                     \
            __builtin_amdgcn_global_load_lds(                                               \
                (const __attribute__((address_space(1))) unsigned int*)g_,                  \
                (__attribute__((address_space(3))) unsigned int*)&(DST)[r_][sec], 16, 0, 0);\
        }                                                                                   \
    }

#define BARRIER do { asm volatile("" ::: "memory"); __builtin_amdgcn_s_barrier(); \
                     asm volatile("" ::: "memory"); } while (0)
#define LGKM0   do { asm volatile("s_waitcnt lgkmcnt(0)" ::: "memory"); \
                     __builtin_amdgcn_sched_barrier(0); } while (0)

#define DS_READ_A(BUF, m, dst)                                                              \
    {                                                                                       \
        const int ra = wm * 64 + ((m) & 3) * 16 + lr;                                       \
        _Pragma("unroll")                                                                   \
        for (int ks = 0; ks < 2; ++ks)                                                      \
            dst[ks] = *(const short8*)&As[BUF][(m) >> 2][ra][(ks * 32 + lk) ^ ((ra & 7) << 3)]; \
    }

#define DS_READ_B(BUF)                                                                      \
    {                                                                                       \
        _Pragma("unroll")                                                                   \
        for (int n = 0; n < 4; ++n) {                                                       \
            const int rb = (wn & 1) * 64 + n * 16 + lr;                                     \
            _Pragma("unroll")                                                               \
            for (int ks = 0; ks < 2; ++ks)                                                  \
                bv[n][ks] = *(const short8*)&Bs[BUF][wn >> 1][rb][(ks * 32 + lk) ^ ((rb & 7) << 3)]; \
        }                                                                                   \
    }

#define MFMA_PH(mb)                                                                         \
    do {                                                                                    \
        __builtin_amdgcn_s_setprio(1);                                                      \
        _Pragma("unroll")                                                                   \
        for (int mi = 0; mi < 2; ++mi)                                                      \
            _Pragma("unroll")                                                               \
            for (int n = 0; n < 4; ++n)                                                     \
                _Pragma("unroll")                                                           \
                for (int ks = 0; ks < 2; ++ks)                                              \
                    acc[(mb) + mi][n] = __builtin_amdgcn_mfma_f32_16x16x32_bf16(            \
                        av[mi][ks], bv[n][ks], acc[(mb) + mi][n], 0, 0, 0);                 \
        __builtin_amdgcn_s_setprio(0);                                                      \
    } while (0)

__global__ __launch_bounds__(512, 2) void kgemm(const ushort* __restrict__ A,
                                                const ushort* __restrict__ B,
                                                float* __restrict__ C,
                                                int M, int N, int K) {
    __shared__ ushort As[2][2][128][64];
    __shared__ ushort Bs[2][2][128][64];

    const int tid = threadIdx.x;
    const int lane = tid & 63;
    const int wid = tid >> 6;      // 0..7
    const int wm = wid >> 2;       // 0..1  (M sub-block within each half)
    const int wn = wid & 3;        // 0..3  (N sub-block)

    // T1: XCD-aware block swizzle (grid % 8 == 0 here)
    int bid = blockIdx.x;
    const int nwg = gridDim.x;
    if ((nwg & 7) == 0) bid = (bid & 7) * (nwg >> 3) + (bid >> 3);
    const int nbn = N >> 8;
    const int bm = bid / nbn, bn = bid % nbn;
    const int row0 = bm << 8, col0 = bn << 8;

    const int lr = lane & 15;
    const int lk = (lane >> 4) * 8;

    // staging thread mapping: 512 threads cover 64 rows x 64 cols per load instr
    const int srow = tid >> 3;          // 0..63
    const int sec  = (tid & 7) * 8;     // element chunk (8 bf16 = 16 B)

    f32x4 acc[8][4] = {};
    const int NT = K >> 6;              // even, >= 2 (K % 128 == 0 guaranteed by launcher)

    // ---- prologue: tile0 (4 halves) + tile1 (first 3 halves); certify tile0
    STAGE_HALF(B, Bs[0][0], col0, 0);
    STAGE_HALF(B, Bs[0][1], col0 + 128, 0);
    STAGE_HALF(A, As[0][0], row0, 0);
    STAGE_HALF(A, As[0][1], row0 + 128, 0);
    STAGE_HALF(B, Bs[1][0], col0, 64);
    STAGE_HALF(B, Bs[1][1], col0 + 128, 64);
    STAGE_HALF(A, As[1][0], row0, 64);
    asm volatile("s_waitcnt vmcnt(6)" ::: "memory");
    BARRIER;

    for (int t = 0; t < NT; t += 2) {
        const int kb1 = (t + 1) << 6;
        const int kb2 = (t + 2 < NT ? t + 2 : NT - 1) << 6;   // clamped tail: region-safe,
        const int kb3 = (t + 3 < NT ? t + 3 : NT - 1) << 6;   // keeps vmcnt ledger exact
        short8 bv[4][2];
        short8 av[2][2];

        // ---- ph1: tile t, quadrant m0-1 (+ all B frags)
        DS_READ_B(0); DS_READ_A(0, 0, av[0]); DS_READ_A(0, 1, av[1]);
        STAGE_HALF(A, As[1][1], row0 + 128, kb1);
        BARRIER; LGKM0; MFMA_PH(0); BARRIER;
        // ---- ph2: m2-3
        DS_READ_A(0, 2, av[0]); DS_READ_A(0, 3, av[1]);
        STAGE_HALF(B, Bs[0][0], col0, kb2);
        BARRIER; LGKM0; MFMA_PH(2); BARRIER;
        // ---- ph3: m4-5
        DS_READ_A(0, 4, av[0]); DS_READ_A(0, 5, av[1]);
        STAGE_HALF(B, Bs[0][1], col0 + 128, kb2);
        BARRIER; LGKM0; MFMA_PH(4); BARRIER;
        // ---- ph4: m6-7; certify tile t+1 (oldest 8 = its 4 halves; >=3 phases slack)
        DS_READ_A(0, 6, av[0]); DS_READ_A(0, 7, av[1]);
        STAGE_HALF(A, As[0][0], row0, kb2);
        asm volatile("s_waitcnt vmcnt(6)" ::: "memory");
        BARRIER; LGKM0; MFMA_PH(6); BARRIER;
        // ---- ph5: tile t+1, m0-1 (+ all B frags)
        DS_READ_B(1); DS_READ_A(1, 0, av[0]); DS_READ_A(1, 1, av[1]);
        STAGE_HALF(A, As[0][1], row0 + 128, kb2);
        BARRIER; LGKM0; MFMA_PH(0); BARRIER;
        // ---- ph6: m2-3
        DS_READ_A(1, 2, av[0]); DS_READ_A(1, 3, av[1]);
        STAGE_HALF(B, Bs[1][0], col0, kb3);
        BARRIER; LGKM0; MFMA_PH(2); BARRIER;
        // ---- ph7: m4-5
        DS_READ_A(1, 4, av[0]); DS_READ_A(1, 5, av[1]);
        STAGE_HALF(B, Bs[1][1], col0 + 128, kb3);
        BARRIER; LGKM0; MFMA_PH(4); BARRIER;
        // ---- ph8: m6-7; certify tile t+2
        DS_READ_A(1, 6, av[0]); DS_READ_A(1, 7, av[1]);
        STAGE_HALF(A, As[1][0], row0, kb3);
        asm volatile("s_waitcnt vmcnt(6)" ::: "memory");
        BARRIER; LGKM0; MFMA_PH(6); BARRIER;
    }
    asm volatile("s_waitcnt vmcnt(0)" ::: "memory");

    // ---- epilogue: C/D layout col = lane&15, row = (lane>>4)*4 + reg (m89-verified)
#pragma unroll
    for (int m = 0; m < 8; ++m) {
        const int grow = row0 + (m >> 2) * 128 + wm * 64 + (m & 3) * 16 + (lane >> 4) * 4;
#pragma unroll
        for (int n = 0; n < 4; ++n) {
            float* cp = C + (size_t)grow * N + col0 + wn * 64 + n * 16 + (lane & 15);
#pragma unroll
            for (int r = 0; r < 4; ++r)
                cp[(size_t)r * N] = acc[m][n][r];
        }
    }
}

// ---------------- correct-but-slow fallback if workspace is tiny ----------------

__global__ void knaive(const float* __restrict__ X, const float* __restrict__ W,
                       const float* __restrict__ gptr, float* __restrict__ out,
                       int N, int K) {
    size_t idx = (size_t)blockIdx.x * blockDim.x + threadIdx.x;
    const int m = (int)(idx / N), n = (int)(idx % N);
    const float g = *gptr;
    const float* xr = X + (size_t)m * K;
    const float* wrow = W + (size_t)n * K;
    float acc = 0.f;
    for (int k = 0; k < K; ++k) {
        float xv = xr[k];
        float xs = (xv > 0.f) ? 1.f : ((xv < 0.f) ? -1.f : 0.f);
        float w = wrow[k];
        float wq = (rintf(fabsf(w) / g) >= 1.f) ? ((w < 0.f) ? -1.f : 1.f) : 0.f;
        acc += xs * wq;
    }
    out[idx] = acc;
}

// ---------------- launch ----------------

extern "C" void kernel_launch(void* const* d_in, const int* in_sizes, int n_in,
                              void* d_out, int out_size, void* d_ws, size_t ws_size,
                              hipStream_t stream) {
    const float* x = (const float*)d_in[0];
    const float* W = (const float*)d_in[1];
    float* out = (float*)d_out;

    const int K = 2048;                 // in_features
    const int N = in_sizes[1] / K;      // out_features = 2048
    const int M = in_sizes[0] / K;      // 4*4096 = 16384
    const int nW = in_sizes[1];

    char* ws = (char*)d_ws;
    double* partials = (double*)ws;                       // 1024 doubles = 8 KB
    float* gamma = (float*)(ws + 8192);
    ushort* wq = (ushort*)(ws + 16384);
    ushort* xq = (ushort*)(ws + 16384 + (size_t)N * K * 2);
    const size_t need = 16384 + (size_t)N * K * 2 + (size_t)M * K * 2;

    kabs_partial<<<1024, 256, 0, stream>>>(W, partials, nW);
    kgamma<<<1, 256, 0, stream>>>(partials, gamma, nW);

    if (ws_size >= need && (M % 256) == 0 && (N % 256) == 0 && (K % 128) == 0) {
        kquant_w<<<nW / (256 * 4), 256, 0, stream>>>((const float4*)W, wq, gamma, nW / 4);
        const size_t n8 = (size_t)M * K / 8;
        kquant_x<<<(unsigned)(n8 / 256), 256, 0, stream>>>((const float4*)x, (uint4*)xq, n8);
        kgemm<<<(M / 256) * (N / 256), 512, 0, stream>>>(xq, wq, out, M, N, K);
    } else {
        knaive<<<(unsigned)((size_t)M * N / 256), 256, 0, stream>>>(x, W, gamma, out, N, K);
    }
}

// Round 8
// 165.745 us; speedup vs baseline: 1.2410x; 1.0560x over previous
//
#include <hip/hip_runtime.h>
#include <hip/hip_bf16.h>

typedef __attribute__((ext_vector_type(8))) short short8;
typedef __attribute__((ext_vector_type(4))) float f32x4;
typedef unsigned short ushort;

// ---------------- gamma = mean(|W|) + 1e-6, deterministic two-stage ----------------

__global__ void kabs_partial(const float* __restrict__ W, double* __restrict__ part, int n) {
    __shared__ double sd[256];
    const int tid = threadIdx.x;
    double s = 0.0;
    for (int i = blockIdx.x * blockDim.x + tid; i < n; i += gridDim.x * blockDim.x)
        s += (double)fabsf(W[i]);
    sd[tid] = s;
    __syncthreads();
    for (int off = 128; off > 0; off >>= 1) {
        if (tid < off) sd[tid] += sd[tid + off];
        __syncthreads();
    }
    if (tid == 0) part[blockIdx.x] = sd[0];
}

__global__ void kgamma(const double* __restrict__ part, float* __restrict__ gout, int nelem) {
    __shared__ double sd[256];
    const int tid = threadIdx.x;
    double s = part[tid] + part[tid + 256] + part[tid + 512] + part[tid + 768];
    sd[tid] = s;
    __syncthreads();
    for (int off = 128; off > 0; off >>= 1) {
        if (tid < off) sd[tid] += sd[tid + off];
        __syncthreads();
    }
    if (tid == 0) gout[0] = (float)(sd[0] / (double)nelem) + 1e-6f;
}

// ---------------- quantizers: write bf16 {-1,0,+1} bit patterns ----------------

__device__ __forceinline__ unsigned int qw_h(float w, float g) {
    float t = fabsf(w) / g;
    unsigned int u = __float_as_uint(w);
    unsigned int h = 0x3F80u | ((u >> 16) & 0x8000u);   // +-1.0 bf16
    return (rintf(t) >= 1.0f) ? h : 0u;
}

__global__ void kquant_w(const float4* __restrict__ W4, unsigned short* __restrict__ Wq,
                         const float* __restrict__ gptr, int n4) {
    int i = blockIdx.x * blockDim.x + threadIdx.x;
    if (i >= n4) return;
    const float g = *gptr;
    float4 w = W4[i];
    unsigned int h0 = qw_h(w.x, g) | (qw_h(w.y, g) << 16);
    unsigned int h1 = qw_h(w.z, g) | (qw_h(w.w, g) << 16);
    ((uint2*)Wq)[i] = make_uint2(h0, h1);
}

__device__ __forceinline__ unsigned int sgn_h(float a) {
    unsigned int u = __float_as_uint(a);
    return (u & 0x7FFFFFFFu) ? (0x3F80u | ((u >> 16) & 0x8000u)) : 0u;
}
__device__ __forceinline__ unsigned int sgn2(float a, float b) {
    return sgn_h(a) | (sgn_h(b) << 16);
}

__global__ void kquant_x(const float4* __restrict__ X4, uint4* __restrict__ Xq, size_t n8) {
    size_t i = (size_t)blockIdx.x * blockDim.x + threadIdx.x;
    if (i >= n8) return;
    float4 a = X4[2 * i], b = X4[2 * i + 1];
    uint4 o;
    o.x = sgn2(a.x, a.y);
    o.y = sgn2(a.z, a.w);
    o.z = sgn2(b.x, b.y);
    o.w = sgn2(b.z, b.w);
    Xq[i] = o;
}

// ---------------- 256x256 8-phase bf16 MFMA GEMM, ONE barrier/phase ----------------
// C[M][N] = A[M][K] * B[N][K]^T. 8 waves (2M x 4N), per-wave 128x64 output.
// Tile tau lives in buf tau&1. Phase p = {STAGE(calendar p); [vmcnt(6) @ph4/ph8];
// BARRIER; lgkmcnt(0)+sched_barrier; setprio(1); 16 MFMA on frags read at p-1;
// setprio(0); ds_read frags for p+1}. Reads overlap co-wave MFMA tails and drain
// during the next barrier wait; MFMA pipe never waits on LDS.
// Safety: stage-into-region at phase q needs last read phase r with q >= r+1
// (reads drain at lgkm0(r) before co-waves pass BARRIER(q)) -- holds for all regions.
// Cross-tile reads (ph4-post: buf1; ph8-post: buf0) follow that phase's certify
// vmcnt(6)+BARRIER. Ledger: 14 outstanding at each certify, drain-8 = one full tile,
// every awaited load >=3 phases old. Tail clamps re-stage identical data into dead
// regions (count-exact, value-safe).

#define STAGE_HALF(SRC, DST, BASE_ROW, KB)                                                  \
    {                                                                                       \
        _Pragma("unroll")                                                                   \
        for (int l = 0; l < 2; ++l) {                                                       \
            const int r_ = l * 64 + srow;                                                   \
            const ushort* g_ = (SRC) + (size_t)((BASE_ROW) + r_) * K + (KB) +               \
                               (sec ^ ((r_ & 7) << 3));                                     \
            __builtin_amdgcn_global_load_lds(                                               \
                (const __attribute__((address_space(1))) unsigned int*)g_,                  \
                (__attribute__((address_space(3))) unsigned int*)&(DST)[r_][sec], 16, 0, 0);\
        }                                                                                   \
    }

#define BARRIER do { asm volatile("" ::: "memory"); __builtin_amdgcn_s_barrier(); \
                     asm volatile("" ::: "memory"); } while (0)
#define LGKM0   do { asm volatile("s_waitcnt lgkmcnt(0)" ::: "memory"); \
                     __builtin_amdgcn_sched_barrier(0); } while (0)
#define VMC6    asm volatile("s_waitcnt vmcnt(6)" ::: "memory")

#define DS_READ_A(BUF, m, dst)                                                              \
    {                                                                                       \
        const int ra = wm * 64 + ((m) & 3) * 16 + lr;                                       \
        _Pragma("unroll")                                                                   \
        for (int ks = 0; ks < 2; ++ks)                                                      \
            dst[ks] = *(const short8*)&As[BUF][(m) >> 2][ra][(ks * 32 + lk) ^ ((ra & 7) << 3)]; \
    }

#define DS_READ_B(BUF)                                                                      \
    {                                                                                       \
        _Pragma("unroll")                                                                   \
        for (int n = 0; n < 4; ++n) {                                                       \
            const int rb = (wn & 1) * 64 + n * 16 + lr;                                     \
            _Pragma("unroll")                                                               \
            for (int ks = 0; ks < 2; ++ks)                                                  \
                bv[n][ks] = *(const short8*)&Bs[BUF][wn >> 1][rb][(ks * 32 + lk) ^ ((rb & 7) << 3)]; \
        }                                                                                   \
    }

#define MFMA_PH(mb, AV)                                                                     \
    do {                                                                                    \
        __builtin_amdgcn_s_setprio(1);                                                      \
        _Pragma("unroll")                                                                   \
        for (int mi = 0; mi < 2; ++mi)                                                      \
            _Pragma("unroll")                                                               \
            for (int n = 0; n < 4; ++n)                                                     \
                _Pragma("unroll")                                                           \
                for (int ks = 0; ks < 2; ++ks)                                              \
                    acc[(mb) + mi][n] = __builtin_amdgcn_mfma_f32_16x16x32_bf16(            \
                        AV[mi][ks], bv[n][ks], acc[(mb) + mi][n], 0, 0, 0);                 \
        __builtin_amdgcn_s_setprio(0);                                                      \
    } while (0)

__global__ __launch_bounds__(512, 2) void kgemm(const ushort* __restrict__ A,
                                                const ushort* __restrict__ B,
                                                float* __restrict__ C,
                                                int M, int N, int K) {
    __shared__ ushort As[2][2][128][64];
    __shared__ ushort Bs[2][2][128][64];

    const int tid = threadIdx.x;
    const int lane = tid & 63;
    const int wid = tid >> 6;      // 0..7
    const int wm = wid >> 2;       // 0..1  (M sub-block within each half)
    const int wn = wid & 3;        // 0..3  (N sub-block)

    // T1: XCD-aware block swizzle (grid % 8 == 0 here)
    int bid = blockIdx.x;
    const int nwg = gridDim.x;
    if ((nwg & 7) == 0) bid = (bid & 7) * (nwg >> 3) + (bid >> 3);
    const int nbn = N >> 8;
    const int bm = bid / nbn, bn = bid % nbn;
    const int row0 = bm << 8, col0 = bn << 8;

    const int lr = lane & 15;
    const int lk = (lane >> 4) * 8;

    // staging thread mapping: 512 threads cover 64 rows x 64 cols per load instr
    const int srow = tid >> 3;          // 0..63
    const int sec  = (tid & 7) * 8;     // element chunk (8 bf16 = 16 B)

    f32x4 acc[8][4] = {};
    const int NT = K >> 6;              // even (K % 128 == 0 guaranteed by launcher)

    // ---- prologue: tile0 (4 halves) + tile1 (3 halves); certify tile0; preload ph1 frags
    STAGE_HALF(B, Bs[0][0], col0, 0);
    STAGE_HALF(B, Bs[0][1], col0 + 128, 0);
    STAGE_HALF(A, As[0][0], row0, 0);
    STAGE_HALF(A, As[0][1], row0 + 128, 0);
    STAGE_HALF(B, Bs[1][0], col0, 64);
    STAGE_HALF(B, Bs[1][1], col0 + 128, 64);
    STAGE_HALF(A, As[1][0], row0, 64);
    VMC6;
    BARRIER;

    short8 bv[4][2], av0[2][2], av1[2][2];
    DS_READ_B(0);
    DS_READ_A(0, 0, av0[0]); DS_READ_A(0, 1, av0[1]);

    for (int t = 0; t < NT; t += 2) {
        const int kb1 = (t + 1) << 6;
        const int kb2 = (t + 2 < NT ? t + 2 : NT - 1) << 6;   // clamped tail: dead-region
        const int kb3 = (t + 3 < NT ? t + 3 : NT - 1) << 6;   // re-stage, ledger exact

        // ph1: MFMA m0-1 (tile t); read m2-3
        STAGE_HALF(A, As[1][1], row0 + 128, kb1);
        BARRIER; LGKM0;
        MFMA_PH(0, av0);
        DS_READ_A(0, 2, av1[0]); DS_READ_A(0, 3, av1[1]);
        // ph2: MFMA m2-3; read m4-5
        STAGE_HALF(B, Bs[0][0], col0, kb2);
        BARRIER; LGKM0;
        MFMA_PH(2, av1);
        DS_READ_A(0, 4, av0[0]); DS_READ_A(0, 5, av0[1]);
        // ph3: MFMA m4-5; read m6-7
        STAGE_HALF(B, Bs[0][1], col0 + 128, kb2);
        BARRIER; LGKM0;
        MFMA_PH(4, av0);
        DS_READ_A(0, 6, av1[0]); DS_READ_A(0, 7, av1[1]);
        // ph4: certify tile t+1; MFMA m6-7; read tile t+1 B + m0-1
        STAGE_HALF(A, As[0][0], row0, kb2);
        VMC6;
        BARRIER; LGKM0;
        MFMA_PH(6, av1);
        DS_READ_B(1);
        DS_READ_A(1, 0, av0[0]); DS_READ_A(1, 1, av0[1]);
        // ph5: MFMA m0-1 (tile t+1); read m2-3
        STAGE_HALF(A, As[0][1], row0 + 128, kb2);
        BARRIER; LGKM0;
        MFMA_PH(0, av0);
        DS_READ_A(1, 2, av1[0]); DS_READ_A(1, 3, av1[1]);
        // ph6: MFMA m2-3; read m4-5
        STAGE_HALF(B, Bs[1][0], col0, kb3);
        BARRIER; LGKM0;
        MFMA_PH(2, av1);
        DS_READ_A(1, 4, av0[0]); DS_READ_A(1, 5, av0[1]);
        // ph7: MFMA m4-5; read m6-7
        STAGE_HALF(B, Bs[1][1], col0 + 128, kb3);
        BARRIER; LGKM0;
        MFMA_PH(4, av0);
        DS_READ_A(1, 6, av1[0]); DS_READ_A(1, 7, av1[1]);
        // ph8: certify tile t+2; MFMA m6-7; read tile t+2 B + m0-1
        STAGE_HALF(A, As[1][0], row0, kb3);
        VMC6;
        BARRIER; LGKM0;
        MFMA_PH(6, av1);
        DS_READ_B(0);
        DS_READ_A(0, 0, av0[0]); DS_READ_A(0, 1, av0[1]);
    }
    asm volatile("s_waitcnt vmcnt(0) lgkmcnt(0)" ::: "memory");

    // ---- epilogue: C/D layout col = lane&15, row = (lane>>4)*4 + reg (m89-verified)
#pragma unroll
    for (int m = 0; m < 8; ++m) {
        const int grow = row0 + (m >> 2) * 128 + wm * 64 + (m & 3) * 16 + (lane >> 4) * 4;
#pragma unroll
        for (int n = 0; n < 4; ++n) {
            float* cp = C + (size_t)grow * N + col0 + wn * 64 + n * 16 + (lane & 15);
#pragma unroll
            for (int r = 0; r < 4; ++r)
                cp[(size_t)r * N] = acc[m][n][r];
        }
    }
}

// ---------------- correct-but-slow fallback if workspace is tiny ----------------

__global__ void knaive(const float* __restrict__ X, const float* __restrict__ W,
                       const float* __restrict__ gptr, float* __restrict__ out,
                       int N, int K) {
    size_t idx = (size_t)blockIdx.x * blockDim.x + threadIdx.x;
    const int m = (int)(idx / N), n = (int)(idx % N);
    const float g = *gptr;
    const float* xr = X + (size_t)m * K;
    const float* wrow = W + (size_t)n * K;
    float acc = 0.f;
    for (int k = 0; k < K; ++k) {
        float xv = xr[k];
        float xs = (xv > 0.f) ? 1.f : ((xv < 0.f) ? -1.f : 0.f);
        float w = wrow[k];
        float wq = (rintf(fabsf(w) / g) >= 1.f) ? ((w < 0.f) ? -1.f : 1.f) : 0.f;
        acc += xs * wq;
    }
    out[idx] = acc;
}

// ---------------- launch ----------------

extern "C" void kernel_launch(void* const* d_in, const int* in_sizes, int n_in,
                              void* d_out, int out_size, void* d_ws, size_t ws_size,
                              hipStream_t stream) {
    const float* x = (const float*)d_in[0];
    const float* W = (const float*)d_in[1];
    float* out = (float*)d_out;

    const int K = 2048;                 // in_features
    const int N = in_sizes[1] / K;      // out_features = 2048
    const int M = in_sizes[0] / K;      // 4*4096 = 16384
    const int nW = in_sizes[1];

    char* ws = (char*)d_ws;
    double* partials = (double*)ws;                       // 1024 doubles = 8 KB
    float* gamma = (float*)(ws + 8192);
    ushort* wq = (ushort*)(ws + 16384);
    ushort* xq = (ushort*)(ws + 16384 + (size_t)N * K * 2);
    const size_t need = 16384 + (size_t)N * K * 2 + (size_t)M * K * 2;

    kabs_partial<<<1024, 256, 0, stream>>>(W, partials, nW);
    kgamma<<<1, 256, 0, stream>>>(partials, gamma, nW);

    if (ws_size >= need && (M % 256) == 0 && (N % 256) == 0 && (K % 128) == 0) {
        kquant_w<<<nW / (256 * 4), 256, 0, stream>>>((const float4*)W, wq, gamma, nW / 4);
        const size_t n8 = (size_t)M * K / 8;
        kquant_x<<<(unsigned)(n8 / 256), 256, 0, stream>>>((const float4*)x, (uint4*)xq, n8);
        kgemm<<<(M / 256) * (N / 256), 512, 0, stream>>>(xq, wq, out, M, N, K);
    } else {
        knaive<<<(unsigned)((size_t)M * N / 256), 256, 0, stream>>>(x, W, gamma, out, N, K);
    }
}